// Round 9
// baseline (363.733 us; speedup 1.0000x reference)
//
#include <hip/hip_runtime.h>
#include <hip/hip_bf16.h>
#include <math.h>

#define B_ 16
#define T_ 512
#define H_ 768
#define S_ 32
#define L_ 50
#define NT_ 3
#define HS_ 3072
#define CH_ 32
#define CT_ 16  // T_/CH_

// A-buffer row layout (bf16, 768 cols):
//   [0, 8192)        hb   = bf16(h), row b*512+t
//   [8192, 16512)    preb = bf16(cumsum), row 8192 + b*513 + t  (8208 valid, pad to 8320)
//   [16512, 17024)   Gb   = gathered span-start rows (512)
// XY-buffer (bf16, 3072 cols): rows 0..16399 = [X rows | Y rows], same row ids as A.
#define XROWS 8192
#define YBASE 8192
#define GBASE 16512
#define XYROWS 16400
#define AROWS 17152   // alloc (128-pad)
// prep mega-kernel block ranges
#define PB_CUM 384        // cumsum pass1: 16*32*192/256
#define PB_TRW 2304       // transpose_w: 48*48
#define PB_GAT 512        // gather: 512 span rows
#define PB_CC  192        // CC gemv: 16 b * 12 n-chunks
#define PB_WB  3          // w_score -> bf16
#define PREP_BLOCKS (PB_CUM + PB_TRW + PB_GAT + PB_CC + PB_WB)

typedef __attribute__((ext_vector_type(8))) short short8;
typedef __attribute__((ext_vector_type(16))) float float16v;

__device__ __forceinline__ unsigned short f2bf(float f) {
    __hip_bfloat16 b = __float2bfloat16(f);
    return *(unsigned short*)&b;
}
__device__ __forceinline__ float bf2f(unsigned short u) {
    union { unsigned int i; float f; } v; v.i = ((unsigned int)u) << 16; return v.f;
}
__device__ __forceinline__ void load_lds16(const void* g, void* l) {
    __builtin_amdgcn_global_load_lds((__attribute__((address_space(1))) void*)g,
                                     (__attribute__((address_space(3))) void*)l, 16, 0, 0);
}
__device__ __forceinline__ ushort4 pack4(float4 v) {
    ushort4 o; o.x = f2bf(v.x); o.y = f2bf(v.y); o.z = f2bf(v.z); o.w = f2bf(v.w);
    return o;
}

// branch-free exact-gelu: Abramowitz-Stegun 3-term erf, max err 2.5e-5
__device__ __forceinline__ float gelu_exact(float v) {
    float a = fabsf(v) * 0.70710678118654752f;
    float t = __builtin_amdgcn_rcpf(fmaf(a, 0.47047f, 1.0f));
    float poly = t * fmaf(t, fmaf(t, 0.7478556f, -0.0958798f), 0.3480242f);
    float e = __builtin_amdgcn_exp2f(a * a * -1.4426950408889634f);
    float erfa = fmaf(-poly, e, 1.0f);
    float erfv = copysignf(erfa, v);
    return 0.5f * v * (1.0f + erfv);
}

// ---------------------------------------------------------------------------
// prep mega-kernel: all inter-independent setup in ONE launch.
//   [0, 384)      cumsum pass1 partial sums
//   [384, 2688)   W1 transpose -> 4 bf16 panels
//   [2688, 3200)  gather span-start rows -> Ab
//   [3200, 3392)  CC[b][d] = h[b,0,:] . W1[2304:3072, d]  (LDS-cached GEMV)
//   [3392, 3395)  w_score -> bf16
// ---------------------------------------------------------------------------
__global__ __launch_bounds__(256) void prep_kernel(
    const float4* __restrict__ h4, const float* __restrict__ h,
    const int* __restrict__ starts, const float* __restrict__ W1,
    const float4* __restrict__ w_score,
    float4* __restrict__ partial, __hip_bfloat16* __restrict__ Ab,
    __hip_bfloat16* __restrict__ Wt, float* __restrict__ CC,
    ushort4* __restrict__ wb16) {
    __shared__ float tile[64][65];
    int bx = blockIdx.x, tid = threadIdx.x;

    if (bx < PB_CUM) {
        int idx = bx * 256 + tid;                    // (b, ch, hd4)
        int hd4 = idx % 192; int t = idx / 192; int ch = t % CH_; int b = t / CH_;
        const float4* hp = h4 + ((size_t)b * T_ + ch * CT_) * 192 + hd4;
        float4 acc = {0.f, 0.f, 0.f, 0.f};
#pragma unroll
        for (int tt = 0; tt < CT_; tt++) {
            float4 v = hp[(size_t)tt * 192];
            acc.x += v.x; acc.y += v.y; acc.z += v.z; acc.w += v.w;
        }
        partial[idx] = acc;
    } else if (bx < PB_CUM + PB_TRW) {
        int q = bx - PB_CUM;
        int n0 = (q % 48) * 64, k0 = (q / 48) * 64;
        int c = tid & 63, r0 = tid >> 6;
#pragma unroll
        for (int i = 0; i < 16; i++) {
            int r = r0 + i * 4;
            tile[r][c] = W1[(size_t)(k0 + r) * HS_ + n0 + c];
        }
        __syncthreads();
        int p = k0 / H_, kl = k0 % H_;
        __hip_bfloat16* out = Wt + (size_t)p * HS_ * H_;
#pragma unroll
        for (int i = 0; i < 16; i++) {
            int r = r0 + i * 4;
            out[(size_t)(n0 + r) * H_ + kl + c] = __float2bfloat16(tile[c][r]);
        }
    } else if (bx < PB_CUM + PB_TRW + PB_GAT) {
        int r = bx - (PB_CUM + PB_TRW);              // 0..511 span rows
        int b = r / S_;
        int sv = starts[r];
        int sc = min(max(sv, 0), T_ - 1);
        const float* src = h + (size_t)(b * T_ + sc) * H_;
        __hip_bfloat16* dst = Ab + (size_t)(GBASE + r) * H_;
        for (int j = tid; j < H_; j += 256)
            dst[j] = __float2bfloat16(src[j]);
    } else if (bx < PB_CUM + PB_TRW + PB_GAT + PB_CC) {
        int q = bx - (PB_CUM + PB_TRW + PB_GAT);
        int b = q / 12, n0 = (q % 12) * 256;
        float* hs = &tile[0][0];                     // reuse LDS (768 floats)
        const float* hrow = h + (size_t)b * T_ * H_; // h[b,0,:]
        for (int j = tid; j < H_; j += 256) hs[j] = hrow[j];
        __syncthreads();
        int d = n0 + tid;
        const float* wp = W1 + (size_t)2304 * HS_ + d;
        float acc = 0.f;
#pragma unroll 8
        for (int k = 0; k < H_; k++) acc = fmaf(hs[k], wp[(size_t)k * HS_], acc);
        CC[(size_t)b * HS_ + d] = acc;
    } else {
        int i = (bx - (PB_CUM + PB_TRW + PB_GAT + PB_CC)) * 256 + tid;  // 0..767
        wb16[i] = pack4(w_score[i]);
    }
}

// pass3 (chunk prefix folded in): emit bf16 h + bf16 cumsum into A buffer
__global__ __launch_bounds__(256) void cumsum_pass3(const float4* __restrict__ h4,
                                                    const float4* __restrict__ partial,
                                                    ushort4* __restrict__ Ab4) {
    int idx = blockIdx.x * 256 + threadIdx.x;        // (b, ch, hd4)
    int hd4 = idx % 192; int t = idx / 192; int ch = t % CH_; int b = t / CH_;
    float4 acc = {0.f, 0.f, 0.f, 0.f};
#pragma unroll
    for (int c = 0; c < CH_; c++) {
        if (c < ch) {
            float4 v = partial[((size_t)b * CH_ + c) * 192 + hd4];
            acc.x += v.x; acc.y += v.y; acc.z += v.z; acc.w += v.w;
        }
    }
    int row0 = b * T_ + ch * CT_;
    const float4* hp = h4 + (size_t)row0 * 192 + hd4;
    ushort4* hb = Ab4 + (size_t)row0 * 192 + hd4;
    ushort4* pp = Ab4 + ((size_t)(YBASE + b * (T_ + 1) + ch * CT_ + 1)) * 192 + hd4;
    if (ch == 0) {
        ushort4 z = {0, 0, 0, 0};
        Ab4[((size_t)(YBASE + b * (T_ + 1))) * 192 + hd4] = z;
    }
#pragma unroll
    for (int tt = 0; tt < CT_; tt++) {
        float4 hv = hp[(size_t)tt * 192];
        hb[(size_t)tt * 192] = pack4(hv);
        acc.x += hv.x; acc.y += hv.y; acc.z += hv.z; acc.w += hv.w;
        pp[(size_t)tt * 192] = pack4(acc);
    }
}

// ---------------------------------------------------------------------------
// mega MFMA GEMM over 17024 A rows (X | Y | ST). ST epilogue fuses +CC[b]+b1
// and writes bf16 c0 directly. 128x128 tile, BK=64, 4 waves, 32x32x16 bf16.
// LDS: [hh][row 128][4 chunks of 16B], physical chunk = logical ^ ((row>>1)&3).
// grid: x = n-tile (24) fastest -> B-slices pin per-XCD L2, A read ~once.
// ---------------------------------------------------------------------------
__global__ __launch_bounds__(256) void mfma_gemm(const __hip_bfloat16* __restrict__ Ab,
                                                 const __hip_bfloat16* __restrict__ Wt,
                                                 const float* __restrict__ CC,
                                                 const float* __restrict__ b1,
                                                 __hip_bfloat16* __restrict__ XY,
                                                 unsigned short* __restrict__ c0b) {
    constexpr int K = H_;
    __shared__ __hip_bfloat16 As[2 * 128 * 32];
    __shared__ __hip_bfloat16 Bs[2 * 128 * 32];
    int tid = threadIdx.x;
    int wave = tid >> 6, lane = tid & 63;
    int n0 = blockIdx.x * 128, m0 = blockIdx.y * 128;
    int wm = (wave & 1) * 64, wn = (wave >> 1) * 64;

    const __hip_bfloat16* Bt;
    if (m0 < XROWS)            Bt = Wt + (size_t)1 * HS_ * H_;  // X: h_end panel
    else if (m0 < GBASE)       Bt = Wt + (size_t)2 * HS_ * H_;  // Y: h_mean panel
    else                       Bt = Wt;                         // ST: h_start panel

    float16v acc[2][2] = {};

    int l31 = lane & 31, lh = lane >> 5;

    for (int k0 = 0; k0 < K; k0 += 64) {
        __syncthreads();
#pragma unroll
        for (int i = 0; i < 4; i++) {
            int cid = i * 256 + wave * 64 + lane;   // 0..1023 physical 16B chunks
            int hh = cid >> 9, row = (cid >> 2) & 127, pc = cid & 3;
            int lc = pc ^ ((row >> 1) & 3);         // logical chunk this slot holds
            size_t go = (size_t)row * K + k0 + hh * 32 + lc * 8;
            load_lds16(Ab + (size_t)m0 * K + go,
                       (char*)As + (size_t)(i * 256 + wave * 64) * 16);
            load_lds16(Bt + (size_t)n0 * K + go,
                       (char*)Bs + (size_t)(i * 256 + wave * 64) * 16);
        }
        __syncthreads();

        const short* Asp = (const short*)As;
        const short* Bsp = (const short*)Bs;
#pragma unroll
        for (int kk = 0; kk < 4; kk++) {
            int hh = kk >> 1;
            int lc = 2 * (kk & 1) + lh;             // logical chunk for this frag
            short8 af[2], bf[2];
#pragma unroll
            for (int mi = 0; mi < 2; mi++) {
                int row = wm + mi * 32 + l31;
                int pc = lc ^ ((row >> 1) & 3);
                af[mi] = *(const short8*)&Asp[(hh * 512 + row * 4 + pc) * 8];
            }
#pragma unroll
            for (int ni = 0; ni < 2; ni++) {
                int row = wn + ni * 32 + l31;
                int pc = lc ^ ((row >> 1) & 3);
                bf[ni] = *(const short8*)&Bsp[(hh * 512 + row * 4 + pc) * 8];
            }
#pragma unroll
            for (int mi = 0; mi < 2; mi++)
#pragma unroll
                for (int ni = 0; ni < 2; ni++)
                    acc[mi][ni] = __builtin_amdgcn_mfma_f32_32x32x16_bf16(
                        af[mi], bf[ni], acc[mi][ni], 0, 0, 0);
        }
    }

    // epilogue: 32x32 C/D layout: col=lane&31, row=(reg&3)+8*(reg>>2)+4*(lane>>5)
#pragma unroll
    for (int mi = 0; mi < 2; mi++) {
#pragma unroll
        for (int ni = 0; ni < 2; ni++) {
            int n = n0 + wn + ni * 32 + l31;
#pragma unroll
            for (int r = 0; r < 16; r++) {
                int m = m0 + wm + mi * 32 + (r & 3) + 8 * (r >> 2) + 4 * lh;
                float v = acc[mi][ni][r];
                if (m < XYROWS) {
                    XY[(size_t)m * HS_ + n] = __float2bfloat16(v);
                } else if (m >= GBASE) {
                    int bsI = m - GBASE;             // 0..511
                    int bb = bsI >> 5;
                    c0b[(size_t)bsI * HS_ + n] =
                        f2bf(v + CC[(size_t)bb * HS_ + n] + b1[n]);
                }
            }
        }
    }
}

// ---------------------------------------------------------------------------
// combine: one wave per (b,s, l-pair); l0=2p, l1=2p+1 share Ys/c0/w streams
// (adjacent X/Y rows for l1). grid (512, 7), 4 waves/block; pairs 0..24.
// ---------------------------------------------------------------------------
__global__ __launch_bounds__(256) void combine_kernel(
    const unsigned short* __restrict__ c0, const unsigned short* __restrict__ wb16,
    const __hip_bfloat16* __restrict__ XY,
    const float* __restrict__ b_score, const float* __restrict__ W_type,
    const int* __restrict__ starts, const int* __restrict__ ends,
    float* __restrict__ scores, float* __restrict__ tgold) {
    int bs = blockIdx.x;
    int b = bs >> 5;
    int wave = threadIdx.x >> 6, lane = threadIdx.x & 63;
    int pr = blockIdx.y * 4 + wave;        // pair index 0..24
    if (pr >= L_ / 2) return;
    int l0 = pr * 2, l1 = l0 + 1;
    int sv = starts[bs], ev = ends[bs];
    int gi = min(max(ev - sv, 0), L_ - 1);
    int sc = min(max(sv, 0), T_ - 1);
    int pc0 = min(max(sv + l0, 0), T_ - 1);
    int pc1 = min(max(sv + l1, 0), T_ - 1);
    float inv0 = 1.0f / (float)(l0 + 1);
    float inv1 = 1.0f / (float)(l1 + 1);
    bool isg0 = (l0 == gi), isg1 = (l1 == gi);
    bool anyg = isg0 || isg1;

    const unsigned short* X0 = (const unsigned short*)(XY + (size_t)(b * T_ + pc0) * HS_);
    const unsigned short* X1 = (const unsigned short*)(XY + (size_t)(b * T_ + pc1) * HS_);
    const unsigned short* Y0 = (const unsigned short*)(XY + (size_t)(YBASE + b * (T_ + 1) + pc0 + 1) * HS_);
    const unsigned short* Y1 = (const unsigned short*)(XY + (size_t)(YBASE + b * (T_ + 1) + pc1 + 1) * HS_);
    const unsigned short* Ysr = (const unsigned short*)(XY + (size_t)(YBASE + b * (T_ + 1) + sc) * HS_);
    const unsigned short* c0r = c0 + (size_t)bs * HS_;

    float local0 = 0.f, local1 = 0.f, t0 = 0.f, t1 = 0.f, t2 = 0.f;
#pragma unroll
    for (int j = 0; j < 6; j++) {
        int d = j * 512 + lane * 8;
        short8 xv0 = *(const short8*)(X0 + d);
        short8 xv1 = *(const short8*)(X1 + d);
        short8 yv0 = *(const short8*)(Y0 + d);
        short8 yv1 = *(const short8*)(Y1 + d);
        short8 sv8 = *(const short8*)(Ysr + d);
        short8 cv8 = *(const short8*)(c0r + d);
        short8 wv8 = *(const short8*)(wb16 + d);
#pragma unroll
        for (int q = 0; q < 8; q++) {
            float ys = bf2f(((const unsigned short*)&sv8)[q]);
            float cv = bf2f(((const unsigned short*)&cv8)[q]);
            float w  = bf2f(((const unsigned short*)&wv8)[q]);
            float v0 = fmaf(bf2f(((const unsigned short*)&yv0)[q]) - ys, inv0, cv) +
                       bf2f(((const unsigned short*)&xv0)[q]);
            float v1 = fmaf(bf2f(((const unsigned short*)&yv1)[q]) - ys, inv1, cv) +
                       bf2f(((const unsigned short*)&xv1)[q]);
            float g0 = gelu_exact(v0);
            float g1 = gelu_exact(v1);
            local0 = fmaf(g0, w, local0);
            local1 = fmaf(g1, w, local1);
            if (anyg) {   // wave-uniform branch
                float gg = isg0 ? g0 : g1;
                t0 = fmaf(gg, W_type[(d + q) * NT_ + 0], t0);
                t1 = fmaf(gg, W_type[(d + q) * NT_ + 1], t1);
                t2 = fmaf(gg, W_type[(d + q) * NT_ + 2], t2);
            }
        }
    }
#pragma unroll
    for (int off = 32; off >= 1; off >>= 1) {
        local0 += __shfl_down(local0, off);
        local1 += __shfl_down(local1, off);
    }
    if (lane == 0) {
        float bs0 = b_score[0];
        scores[(size_t)bs * L_ + l0] = local0 + bs0;
        scores[(size_t)bs * L_ + l1] = local1 + bs0;
    }
    if (anyg) {
#pragma unroll
        for (int off = 32; off >= 1; off >>= 1) {
            t0 += __shfl_down(t0, off);
            t1 += __shfl_down(t1, off);
            t2 += __shfl_down(t2, off);
        }
        if (lane == 0) {
            tgold[bs * NT_ + 0] = t0;
            tgold[bs * NT_ + 1] = t1;
            tgold[bs * NT_ + 2] = t2;
        }
    }
}

// ---------------------------------------------------------------------------
// final loss: one block, one thread per (b,s)
// ---------------------------------------------------------------------------
__global__ __launch_bounds__(512) void loss_kernel(
    const float* __restrict__ scores, const float* __restrict__ tgold,
    const int* __restrict__ mask, const int* __restrict__ starts,
    const int* __restrict__ ends, const int* __restrict__ types,
    const float* __restrict__ b_type, float* __restrict__ out) {
    __shared__ int svl[B_];
    __shared__ float r[3][8];
    int tid = threadIdx.x;
    int b = tid / S_;
    if (tid < B_) svl[tid] = 0;
    __syncthreads();
    {
        int part = 0;
        const int* mp = mask + tid * 16;
#pragma unroll
        for (int i = 0; i < 16; i++) part += mp[i];
        atomicAdd(&svl[tid / (T_ / 16)], part);
    }
    __syncthreads();
    int vl = svl[b];
    int lt = max(1, vl - 2);
    int sv = starts[tid], ev = ends[tid];
    int gold = ev - sv;
    bool valid = (sv >= 1) && (sv <= lt) && (ev >= sv) && (ev <= lt) && (gold < L_);
    int emax = min(sv + L_ - 1, lt);
    const float* sp = scores + (size_t)tid * L_;
    float m = -1e30f;
    for (int l = 0; l < L_; l++) {
        float v = (sv + l <= emax) ? sp[l] : -1e9f;
        m = fmaxf(m, v);
    }
    float sum = 0.f;
    for (int l = 0; l < L_; l++) {
        float v = (sv + l <= emax) ? sp[l] : -1e9f;
        sum += expf(v - m);
    }
    int gi = min(max(gold, 0), L_ - 1);
    float vg = (sv + gi <= emax) ? sp[gi] : -1e9f;
    float end_loss = (m + logf(sum)) - vg;

    float t0 = tgold[tid * 3 + 0] + b_type[0];
    float t1 = tgold[tid * 3 + 1] + b_type[1];
    float t2 = tgold[tid * 3 + 2] + b_type[2];
    float tm = fmaxf(t0, fmaxf(t1, t2));
    float tsum = expf(t0 - tm) + expf(t1 - tm) + expf(t2 - tm);
    int tg = min(max(types[tid], 0), NT_ - 1);
    float tv = (tg == 0) ? t0 : ((tg == 1) ? t1 : t2);
    float type_loss = (tm + logf(tsum)) - tv;

    float ve = valid ? end_loss : 0.f;
    float vt = valid ? type_loss : 0.f;
    float vc = valid ? 1.f : 0.f;
    for (int off = 32; off >= 1; off >>= 1) {
        ve += __shfl_down(ve, off);
        vt += __shfl_down(vt, off);
        vc += __shfl_down(vc, off);
    }
    if ((tid & 63) == 0) {
        int w = tid >> 6;
        r[0][w] = ve; r[1][w] = vt; r[2][w] = vc;
    }
    __syncthreads();
    if (tid == 0) {
        float se = 0, st = 0, n = 0;
        for (int w = 0; w < 8; w++) { se += r[0][w]; st += r[1][w]; n += r[2][w]; }
        float denom = fmaxf(n, 1.f);
        out[0] = (n > 0.f) ? (se / denom + st / denom) : 0.f;
    }
}

// ---------------------------------------------------------------------------
extern "C" void kernel_launch(void* const* d_in, const int* in_sizes, int n_in,
                              void* d_out, int out_size, void* d_ws, size_t ws_size,
                              hipStream_t stream) {
    const float* h       = (const float*)d_in[0];
    const int*   mask    = (const int*)d_in[1];
    const int*   starts  = (const int*)d_in[2];
    const int*   ends    = (const int*)d_in[3];
    const int*   types   = (const int*)d_in[4];
    const float* W1      = (const float*)d_in[5];
    const float* b1      = (const float*)d_in[6];
    const float* w_score = (const float*)d_in[7];
    const float* b_score = (const float*)d_in[8];
    const float* W_type  = (const float*)d_in[9];
    const float* b_type  = (const float*)d_in[10];
    float* out = (float*)d_out;

    char* ws = (char*)d_ws;
    size_t off = 0;
    __hip_bfloat16* Ab = (__hip_bfloat16*)(ws + off); off += (size_t)AROWS * H_ * 2;
    __hip_bfloat16* XY = (__hip_bfloat16*)(ws + off); off += (size_t)XYROWS * HS_ * 2;
    __hip_bfloat16* Wt = (__hip_bfloat16*)(ws + off); off += (size_t)4 * HS_ * H_ * 2;
    float* CC     = (float*)(ws + off);               off += (size_t)16 * HS_ * 4;
    unsigned short* c0b = (unsigned short*)(ws + off); off += (size_t)512 * HS_ * 2;
    unsigned short* wb16 = (unsigned short*)(ws + off); off += (size_t)HS_ * 2;
    float* scores = (float*)(ws + off);               off += (size_t)B_ * S_ * L_ * 4;
    float* tgold  = (float*)(ws + off);               off += (size_t)B_ * S_ * NT_ * 4;
    float4* partial = (float4*)XY;  // aliases XY; consumed by pass3 before GEMM writes XY

    hipLaunchKernelGGL(prep_kernel, dim3(PREP_BLOCKS), dim3(256), 0, stream,
                       (const float4*)h, h, starts, W1, (const float4*)w_score,
                       partial, Ab, Wt, CC, (ushort4*)wb16);
    hipLaunchKernelGGL(cumsum_pass3, dim3(B_ * CH_ * 192 / 256), dim3(256), 0, stream,
                       (const float4*)h, (const float4*)partial, (ushort4*)Ab);
    hipLaunchKernelGGL(mfma_gemm, dim3(24, (GBASE + 512) / 128), dim3(256), 0, stream,
                       Ab, Wt, CC, b1, XY, c0b);
    hipLaunchKernelGGL(combine_kernel, dim3(B_ * S_, 7), dim3(256), 0, stream,
                       c0b, wb16, XY, b_score, W_type, starts, ends, scores, tgold);
    hipLaunchKernelGGL(loss_kernel, dim3(1), dim3(512), 0, stream,
                       scores, tgold, mask, starts, ends, types, b_type, out);
}

// Round 10
// 357.277 us; speedup vs baseline: 1.0181x; 1.0181x over previous
//
#include <hip/hip_runtime.h>
#include <hip/hip_bf16.h>
#include <math.h>

#define B_ 16
#define T_ 512
#define H_ 768
#define S_ 32
#define L_ 50
#define NT_ 3
#define HS_ 3072
#define CH_ 32
#define CT_ 16  // T_/CH_

// Row compaction: starts in [1,400), L=50  =>  pc <= 448, pre-index <= 449.
// TX_=456 rows/batch cover all live rows (8 rows of safety margin).
#define TX_ 456
// A-buffer row layout (bf16, 768 cols), compacted:
//   [0, 7296)        hb   = bf16(h[b,t]), row b*456+t, t<456
//   [7296, 14592)    preb = bf16(cumsum), row 7296 + b*456 + u  (pre[b][u], u<456)
//   [14592, 15104)   Gb   = gathered span-start rows (512)
// XY-buffer (bf16, 3072 cols): rows 0..14591 = [X | Y], same row ids as A.
#define YB2 7296
#define STB 14592
#define XYROWS 14592
#define AROWS 15104        // = 118 * 128 exactly
// prep mega-kernel block ranges
#define PB_CUM 384        // cumsum pass1: 16*32*192/256
#define PB_TRW 2304       // transpose_w: 48*48
#define PB_GAT 512        // gather: 512 span rows
#define PB_CC  192        // CC gemv: 16 b * 12 n-chunks
#define PB_WB  3          // w_score -> bf16
#define PREP_BLOCKS (PB_CUM + PB_TRW + PB_GAT + PB_CC + PB_WB)

typedef __attribute__((ext_vector_type(8))) short short8;
typedef __attribute__((ext_vector_type(16))) float float16v;

__device__ __forceinline__ unsigned short f2bf(float f) {
    __hip_bfloat16 b = __float2bfloat16(f);
    return *(unsigned short*)&b;
}
__device__ __forceinline__ float bf2f(unsigned short u) {
    union { unsigned int i; float f; } v; v.i = ((unsigned int)u) << 16; return v.f;
}
__device__ __forceinline__ void load_lds16(const void* g, void* l) {
    __builtin_amdgcn_global_load_lds((__attribute__((address_space(1))) void*)g,
                                     (__attribute__((address_space(3))) void*)l, 16, 0, 0);
}
__device__ __forceinline__ ushort4 pack4(float4 v) {
    ushort4 o; o.x = f2bf(v.x); o.y = f2bf(v.y); o.z = f2bf(v.z); o.w = f2bf(v.w);
    return o;
}

// branch-free exact-gelu: Abramowitz-Stegun 3-term erf, max err 2.5e-5
__device__ __forceinline__ float gelu_exact(float v) {
    float a = fabsf(v) * 0.70710678118654752f;
    float t = __builtin_amdgcn_rcpf(fmaf(a, 0.47047f, 1.0f));
    float poly = t * fmaf(t, fmaf(t, 0.7478556f, -0.0958798f), 0.3480242f);
    float e = __builtin_amdgcn_exp2f(a * a * -1.4426950408889634f);
    float erfa = fmaf(-poly, e, 1.0f);
    float erfv = copysignf(erfa, v);
    return 0.5f * v * (1.0f + erfv);
}

// ---------------------------------------------------------------------------
// prep mega-kernel: all inter-independent setup in ONE launch.
// ---------------------------------------------------------------------------
__global__ __launch_bounds__(256) void prep_kernel(
    const float4* __restrict__ h4, const float* __restrict__ h,
    const int* __restrict__ starts, const float* __restrict__ W1,
    const float4* __restrict__ w_score,
    float4* __restrict__ partial, __hip_bfloat16* __restrict__ Ab,
    __hip_bfloat16* __restrict__ Wt, float* __restrict__ CC,
    ushort4* __restrict__ wb16) {
    __shared__ float tile[64][65];
    int bx = blockIdx.x, tid = threadIdx.x;

    if (bx < PB_CUM) {
        int idx = bx * 256 + tid;                    // (b, ch, hd4)
        int hd4 = idx % 192; int t = idx / 192; int ch = t % CH_; int b = t / CH_;
        const float4* hp = h4 + ((size_t)b * T_ + ch * CT_) * 192 + hd4;
        float4 acc = {0.f, 0.f, 0.f, 0.f};
#pragma unroll
        for (int tt = 0; tt < CT_; tt++) {
            float4 v = hp[(size_t)tt * 192];
            acc.x += v.x; acc.y += v.y; acc.z += v.z; acc.w += v.w;
        }
        partial[idx] = acc;
    } else if (bx < PB_CUM + PB_TRW) {
        int q = bx - PB_CUM;
        int n0 = (q % 48) * 64, k0 = (q / 48) * 64;
        int c = tid & 63, r0 = tid >> 6;
#pragma unroll
        for (int i = 0; i < 16; i++) {
            int r = r0 + i * 4;
            tile[r][c] = W1[(size_t)(k0 + r) * HS_ + n0 + c];
        }
        __syncthreads();
        int p = k0 / H_, kl = k0 % H_;
        __hip_bfloat16* out = Wt + (size_t)p * HS_ * H_;
#pragma unroll
        for (int i = 0; i < 16; i++) {
            int r = r0 + i * 4;
            out[(size_t)(n0 + r) * H_ + kl + c] = __float2bfloat16(tile[c][r]);
        }
    } else if (bx < PB_CUM + PB_TRW + PB_GAT) {
        int r = bx - (PB_CUM + PB_TRW);              // 0..511 span rows
        int b = r / S_;
        int sv = starts[r];
        int sc = min(max(sv, 0), T_ - 1);
        const float* src = h + (size_t)(b * T_ + sc) * H_;
        __hip_bfloat16* dst = Ab + (size_t)(STB + r) * H_;
        for (int j = tid; j < H_; j += 256)
            dst[j] = __float2bfloat16(src[j]);
    } else if (bx < PB_CUM + PB_TRW + PB_GAT + PB_CC) {
        int q = bx - (PB_CUM + PB_TRW + PB_GAT);
        int b = q / 12, n0 = (q % 12) * 256;
        float* hs = &tile[0][0];                     // reuse LDS (768 floats)
        const float* hrow = h + (size_t)b * T_ * H_; // h[b,0,:]
        for (int j = tid; j < H_; j += 256) hs[j] = hrow[j];
        __syncthreads();
        int d = n0 + tid;
        const float* wp = W1 + (size_t)2304 * HS_ + d;
        float acc = 0.f;
#pragma unroll 8
        for (int k = 0; k < H_; k++) acc = fmaf(hs[k], wp[(size_t)k * HS_], acc);
        CC[(size_t)b * HS_ + d] = acc;
    } else {
        int i = (bx - (PB_CUM + PB_TRW + PB_GAT + PB_CC)) * 256 + tid;  // 0..767
        wb16[i] = pack4(w_score[i]);
    }
}

// pass3 (chunk prefix folded in): emit bf16 h + bf16 cumsum into compacted A.
// Dead chunks (all t >= TX_) early-out.
__global__ __launch_bounds__(256) void cumsum_pass3(const float4* __restrict__ h4,
                                                    const float4* __restrict__ partial,
                                                    ushort4* __restrict__ Ab4) {
    int idx = blockIdx.x * 256 + threadIdx.x;        // (b, ch, hd4)
    int hd4 = idx % 192; int t = idx / 192; int ch = t % CH_; int b = t / CH_;
    if (ch * CT_ >= TX_) return;                     // dead chunk
    float4 acc = {0.f, 0.f, 0.f, 0.f};
#pragma unroll
    for (int c = 0; c < CH_; c++) {
        if (c < ch) {
            float4 v = partial[((size_t)b * CH_ + c) * 192 + hd4];
            acc.x += v.x; acc.y += v.y; acc.z += v.z; acc.w += v.w;
        }
    }
    const float4* hp = h4 + ((size_t)b * T_ + ch * CT_) * 192 + hd4;
    if (ch == 0) {
        ushort4 z = {0, 0, 0, 0};
        Ab4[((size_t)(YB2 + b * TX_)) * 192 + hd4] = z;   // pre[b][0] = 0
    }
#pragma unroll
    for (int tt = 0; tt < CT_; tt++) {
        int t2 = ch * CT_ + tt;
        float4 hv = hp[(size_t)tt * 192];
        if (t2 < TX_)
            Ab4[((size_t)(b * TX_ + t2)) * 192 + hd4] = pack4(hv);
        acc.x += hv.x; acc.y += hv.y; acc.z += hv.z; acc.w += hv.w;
        if (t2 + 1 < TX_)
            Ab4[((size_t)(YB2 + b * TX_ + t2 + 1)) * 192 + hd4] = pack4(acc);
    }
}

// ---------------------------------------------------------------------------
// mega MFMA GEMM over 15104 compacted A rows (X | Y | ST). ST epilogue fuses
// +CC[b]+b1, writes bf16 c0. 128x128 tile, BK=64, 4 waves, 32x32x16 bf16.
// LDS: [hh][row 128][4 chunks of 16B], physical chunk = logical ^ ((row>>1)&3).
// grid: x = n-tile (24) fastest -> B-slices pin per-XCD L2, A read ~once.
// ---------------------------------------------------------------------------
__global__ __launch_bounds__(256) void mfma_gemm(const __hip_bfloat16* __restrict__ Ab,
                                                 const __hip_bfloat16* __restrict__ Wt,
                                                 const float* __restrict__ CC,
                                                 const float* __restrict__ b1,
                                                 __hip_bfloat16* __restrict__ XY,
                                                 unsigned short* __restrict__ c0b) {
    constexpr int K = H_;
    __shared__ __hip_bfloat16 As[2 * 128 * 32];
    __shared__ __hip_bfloat16 Bs[2 * 128 * 32];
    int tid = threadIdx.x;
    int wave = tid >> 6, lane = tid & 63;
    int n0 = blockIdx.x * 128, m0 = blockIdx.y * 128;
    int wm = (wave & 1) * 64, wn = (wave >> 1) * 64;

    const __hip_bfloat16* Bt;
    if (m0 < YB2)        Bt = Wt + (size_t)1 * HS_ * H_;  // X: h_end panel
    else if (m0 < STB)   Bt = Wt + (size_t)2 * HS_ * H_;  // Y: h_mean panel
    else                 Bt = Wt;                         // ST: h_start panel

    float16v acc[2][2] = {};

    int l31 = lane & 31, lh = lane >> 5;

    for (int k0 = 0; k0 < K; k0 += 64) {
        __syncthreads();
#pragma unroll
        for (int i = 0; i < 4; i++) {
            int cid = i * 256 + wave * 64 + lane;   // 0..1023 physical 16B chunks
            int hh = cid >> 9, row = (cid >> 2) & 127, pc = cid & 3;
            int lc = pc ^ ((row >> 1) & 3);         // logical chunk this slot holds
            size_t go = (size_t)row * K + k0 + hh * 32 + lc * 8;
            load_lds16(Ab + (size_t)m0 * K + go,
                       (char*)As + (size_t)(i * 256 + wave * 64) * 16);
            load_lds16(Bt + (size_t)n0 * K + go,
                       (char*)Bs + (size_t)(i * 256 + wave * 64) * 16);
        }
        __syncthreads();

        const short* Asp = (const short*)As;
        const short* Bsp = (const short*)Bs;
#pragma unroll
        for (int kk = 0; kk < 4; kk++) {
            int hh = kk >> 1;
            int lc = 2 * (kk & 1) + lh;             // logical chunk for this frag
            short8 af[2], bf[2];
#pragma unroll
            for (int mi = 0; mi < 2; mi++) {
                int row = wm + mi * 32 + l31;
                int pc = lc ^ ((row >> 1) & 3);
                af[mi] = *(const short8*)&Asp[(hh * 512 + row * 4 + pc) * 8];
            }
#pragma unroll
            for (int ni = 0; ni < 2; ni++) {
                int row = wn + ni * 32 + l31;
                int pc = lc ^ ((row >> 1) & 3);
                bf[ni] = *(const short8*)&Bsp[(hh * 512 + row * 4 + pc) * 8];
            }
#pragma unroll
            for (int mi = 0; mi < 2; mi++)
#pragma unroll
                for (int ni = 0; ni < 2; ni++)
                    acc[mi][ni] = __builtin_amdgcn_mfma_f32_32x32x16_bf16(
                        af[mi], bf[ni], acc[mi][ni], 0, 0, 0);
        }
    }

    // epilogue: 32x32 C/D layout: col=lane&31, row=(reg&3)+8*(reg>>2)+4*(lane>>5)
#pragma unroll
    for (int mi = 0; mi < 2; mi++) {
#pragma unroll
        for (int ni = 0; ni < 2; ni++) {
            int n = n0 + wn + ni * 32 + l31;
#pragma unroll
            for (int r = 0; r < 16; r++) {
                int m = m0 + wm + mi * 32 + (r & 3) + 8 * (r >> 2) + 4 * lh;
                float v = acc[mi][ni][r];
                if (m < XYROWS) {
                    XY[(size_t)m * HS_ + n] = __float2bfloat16(v);
                } else {
                    int bsI = m - STB;               // 0..511
                    int bb = bsI >> 5;
                    c0b[(size_t)bsI * HS_ + n] =
                        f2bf(v + CC[(size_t)bb * HS_ + n] + b1[n]);
                }
            }
        }
    }
}

// ---------------------------------------------------------------------------
// combine: one wave per (b,s, l-pair); l0=2p, l1=2p+1 share Ys/c0/w streams
// (adjacent X/Y rows for l1). grid (512, 7), 4 waves/block; pairs 0..24.
// ---------------------------------------------------------------------------
__global__ __launch_bounds__(256) void combine_kernel(
    const unsigned short* __restrict__ c0, const unsigned short* __restrict__ wb16,
    const __hip_bfloat16* __restrict__ XY,
    const float* __restrict__ b_score, const float* __restrict__ W_type,
    const int* __restrict__ starts, const int* __restrict__ ends,
    float* __restrict__ scores, float* __restrict__ tgold) {
    int bs = blockIdx.x;
    int b = bs >> 5;
    int wave = threadIdx.x >> 6, lane = threadIdx.x & 63;
    int pr = blockIdx.y * 4 + wave;        // pair index 0..24
    if (pr >= L_ / 2) return;
    int l0 = pr * 2, l1 = l0 + 1;
    int sv = starts[bs], ev = ends[bs];
    int gi = min(max(ev - sv, 0), L_ - 1);
    int sc = min(max(sv, 0), TX_ - 1);
    int pc0 = min(max(sv + l0, 0), TX_ - 2);   // spec: <=448; clamp keeps in-bounds
    int pc1 = min(max(sv + l1, 0), TX_ - 2);
    float inv0 = 1.0f / (float)(l0 + 1);
    float inv1 = 1.0f / (float)(l1 + 1);
    bool isg0 = (l0 == gi), isg1 = (l1 == gi);
    bool anyg = isg0 || isg1;

    const unsigned short* X0 = (const unsigned short*)(XY + (size_t)(b * TX_ + pc0) * HS_);
    const unsigned short* X1 = (const unsigned short*)(XY + (size_t)(b * TX_ + pc1) * HS_);
    const unsigned short* Y0 = (const unsigned short*)(XY + (size_t)(YB2 + b * TX_ + pc0 + 1) * HS_);
    const unsigned short* Y1 = (const unsigned short*)(XY + (size_t)(YB2 + b * TX_ + pc1 + 1) * HS_);
    const unsigned short* Ysr = (const unsigned short*)(XY + (size_t)(YB2 + b * TX_ + sc) * HS_);
    const unsigned short* c0r = c0 + (size_t)bs * HS_;

    float local0 = 0.f, local1 = 0.f, t0 = 0.f, t1 = 0.f, t2 = 0.f;
#pragma unroll
    for (int j = 0; j < 6; j++) {
        int d = j * 512 + lane * 8;
        short8 xv0 = *(const short8*)(X0 + d);
        short8 xv1 = *(const short8*)(X1 + d);
        short8 yv0 = *(const short8*)(Y0 + d);
        short8 yv1 = *(const short8*)(Y1 + d);
        short8 sv8 = *(const short8*)(Ysr + d);
        short8 cv8 = *(const short8*)(c0r + d);
        short8 wv8 = *(const short8*)(wb16 + d);
#pragma unroll
        for (int q = 0; q < 8; q++) {
            float ys = bf2f(((const unsigned short*)&sv8)[q]);
            float cv = bf2f(((const unsigned short*)&cv8)[q]);
            float w  = bf2f(((const unsigned short*)&wv8)[q]);
            float v0 = fmaf(bf2f(((const unsigned short*)&yv0)[q]) - ys, inv0, cv) +
                       bf2f(((const unsigned short*)&xv0)[q]);
            float v1 = fmaf(bf2f(((const unsigned short*)&yv1)[q]) - ys, inv1, cv) +
                       bf2f(((const unsigned short*)&xv1)[q]);
            float g0 = gelu_exact(v0);
            float g1 = gelu_exact(v1);
            local0 = fmaf(g0, w, local0);
            local1 = fmaf(g1, w, local1);
            if (anyg) {   // wave-uniform branch
                float gg = isg0 ? g0 : g1;
                t0 = fmaf(gg, W_type[(d + q) * NT_ + 0], t0);
                t1 = fmaf(gg, W_type[(d + q) * NT_ + 1], t1);
                t2 = fmaf(gg, W_type[(d + q) * NT_ + 2], t2);
            }
        }
    }
#pragma unroll
    for (int off = 32; off >= 1; off >>= 1) {
        local0 += __shfl_down(local0, off);
        local1 += __shfl_down(local1, off);
    }
    if (lane == 0) {
        float bs0 = b_score[0];
        scores[(size_t)bs * L_ + l0] = local0 + bs0;
        scores[(size_t)bs * L_ + l1] = local1 + bs0;
    }
    if (anyg) {
#pragma unroll
        for (int off = 32; off >= 1; off >>= 1) {
            t0 += __shfl_down(t0, off);
            t1 += __shfl_down(t1, off);
            t2 += __shfl_down(t2, off);
        }
        if (lane == 0) {
            tgold[bs * NT_ + 0] = t0;
            tgold[bs * NT_ + 1] = t1;
            tgold[bs * NT_ + 2] = t2;
        }
    }
}

// ---------------------------------------------------------------------------
// final loss: one block, one thread per (b,s)
// ---------------------------------------------------------------------------
__global__ __launch_bounds__(512) void loss_kernel(
    const float* __restrict__ scores, const float* __restrict__ tgold,
    const int* __restrict__ mask, const int* __restrict__ starts,
    const int* __restrict__ ends, const int* __restrict__ types,
    const float* __restrict__ b_type, float* __restrict__ out) {
    __shared__ int svl[B_];
    __shared__ float r[3][8];
    int tid = threadIdx.x;
    int b = tid / S_;
    if (tid < B_) svl[tid] = 0;
    __syncthreads();
    {
        int part = 0;
        const int* mp = mask + tid * 16;
#pragma unroll
        for (int i = 0; i < 16; i++) part += mp[i];
        atomicAdd(&svl[tid / (T_ / 16)], part);
    }
    __syncthreads();
    int vl = svl[b];
    int lt = max(1, vl - 2);
    int sv = starts[tid], ev = ends[tid];
    int gold = ev - sv;
    bool valid = (sv >= 1) && (sv <= lt) && (ev >= sv) && (ev <= lt) && (gold < L_);
    int emax = min(sv + L_ - 1, lt);
    const float* sp = scores + (size_t)tid * L_;
    float m = -1e30f;
    for (int l = 0; l < L_; l++) {
        float v = (sv + l <= emax) ? sp[l] : -1e9f;
        m = fmaxf(m, v);
    }
    float sum = 0.f;
    for (int l = 0; l < L_; l++) {
        float v = (sv + l <= emax) ? sp[l] : -1e9f;
        sum += expf(v - m);
    }
    int gi = min(max(gold, 0), L_ - 1);
    float vg = (sv + gi <= emax) ? sp[gi] : -1e9f;
    float end_loss = (m + logf(sum)) - vg;

    float t0 = tgold[tid * 3 + 0] + b_type[0];
    float t1 = tgold[tid * 3 + 1] + b_type[1];
    float t2 = tgold[tid * 3 + 2] + b_type[2];
    float tm = fmaxf(t0, fmaxf(t1, t2));
    float tsum = expf(t0 - tm) + expf(t1 - tm) + expf(t2 - tm);
    int tg = min(max(types[tid], 0), NT_ - 1);
    float tv = (tg == 0) ? t0 : ((tg == 1) ? t1 : t2);
    float type_loss = (tm + logf(tsum)) - tv;

    float ve = valid ? end_loss : 0.f;
    float vt = valid ? type_loss : 0.f;
    float vc = valid ? 1.f : 0.f;
    for (int off = 32; off >= 1; off >>= 1) {
        ve += __shfl_down(ve, off);
        vt += __shfl_down(vt, off);
        vc += __shfl_down(vc, off);
    }
    if ((tid & 63) == 0) {
        int w = tid >> 6;
        r[0][w] = ve; r[1][w] = vt; r[2][w] = vc;
    }
    __syncthreads();
    if (tid == 0) {
        float se = 0, st = 0, n = 0;
        for (int w = 0; w < 8; w++) { se += r[0][w]; st += r[1][w]; n += r[2][w]; }
        float denom = fmaxf(n, 1.f);
        out[0] = (n > 0.f) ? (se / denom + st / denom) : 0.f;
    }
}

// ---------------------------------------------------------------------------
extern "C" void kernel_launch(void* const* d_in, const int* in_sizes, int n_in,
                              void* d_out, int out_size, void* d_ws, size_t ws_size,
                              hipStream_t stream) {
    const float* h       = (const float*)d_in[0];
    const int*   mask    = (const int*)d_in[1];
    const int*   starts  = (const int*)d_in[2];
    const int*   ends    = (const int*)d_in[3];
    const int*   types   = (const int*)d_in[4];
    const float* W1      = (const float*)d_in[5];
    const float* b1      = (const float*)d_in[6];
    const float* w_score = (const float*)d_in[7];
    const float* b_score = (const float*)d_in[8];
    const float* W_type  = (const float*)d_in[9];
    const float* b_type  = (const float*)d_in[10];
    float* out = (float*)d_out;

    char* ws = (char*)d_ws;
    size_t off = 0;
    __hip_bfloat16* Ab = (__hip_bfloat16*)(ws + off); off += (size_t)AROWS * H_ * 2;
    __hip_bfloat16* XY = (__hip_bfloat16*)(ws + off); off += (size_t)XYROWS * HS_ * 2;
    __hip_bfloat16* Wt = (__hip_bfloat16*)(ws + off); off += (size_t)3 * HS_ * H_ * 2;
    float* CC     = (float*)(ws + off);               off += (size_t)16 * HS_ * 4;
    unsigned short* c0b = (unsigned short*)(ws + off); off += (size_t)512 * HS_ * 2;
    unsigned short* wb16 = (unsigned short*)(ws + off); off += (size_t)HS_ * 2;
    float* scores = (float*)(ws + off);               off += (size_t)B_ * S_ * L_ * 4;
    float* tgold  = (float*)(ws + off);               off += (size_t)B_ * S_ * NT_ * 4;
    float4* partial = (float4*)XY;  // aliases XY; consumed by pass3 before GEMM writes XY

    hipLaunchKernelGGL(prep_kernel, dim3(PREP_BLOCKS), dim3(256), 0, stream,
                       (const float4*)h, h, starts, W1, (const float4*)w_score,
                       partial, Ab, Wt, CC, (ushort4*)wb16);
    hipLaunchKernelGGL(cumsum_pass3, dim3(B_ * CH_ * 192 / 256), dim3(256), 0, stream,
                       (const float4*)h, (const float4*)partial, (ushort4*)Ab);
    hipLaunchKernelGGL(mfma_gemm, dim3(24, AROWS / 128), dim3(256), 0, stream,
                       Ab, Wt, CC, b1, XY, c0b);
    hipLaunchKernelGGL(combine_kernel, dim3(B_ * S_, 7), dim3(256), 0, stream,
                       c0b, wb16, XY, b_score, W_type, starts, ends, scores, tgold);
    hipLaunchKernelGGL(loss_kernel, dim3(1), dim3(512), 0, stream,
                       scores, tgold, mask, starts, ends, types, b_type, out);
}

// Round 11
// 354.557 us; speedup vs baseline: 1.0259x; 1.0077x over previous
//
#include <hip/hip_runtime.h>
#include <hip/hip_bf16.h>
#include <math.h>

#define B_ 16
#define T_ 512
#define H_ 768
#define S_ 32
#define L_ 50
#define NT_ 3
#define HS_ 3072
#define CH_ 32
#define CT_ 16  // T_/CH_

// Row compaction: starts in [1,400), L=50  =>  pc <= 448, pre-index <= 449.
// TX_=456 rows/batch cover all live rows (safety margin + clamps).
#define TX_ 456
// A-buffer row layout (bf16, 768 cols), compacted:
//   [0, 7296)        hb   = bf16(h[b,t]), row b*456+t, t<456
//   [7296, 14592)    preb = bf16(cumsum), row 7296 + b*456 + u  (pre[b][u], u<456)
//   [14592, 15104)   Gb   = gathered span-start rows (512)
// XY-buffer (bf16, 3072 cols): rows 0..14591 = [X | Y], same row ids as A.
#define YB2 7296
#define STB 14592
#define XYROWS 14592
#define AROWS 15104        // = 118 * 128 exactly
// prep mega-kernel block ranges
#define PB_CUM 384        // cumsum pass1: 16*32*192/256
#define PB_TRW 2304       // transpose_w: 48*48
#define PB_GAT 512        // gather: 512 span rows
#define PB_CC  192        // CC gemv: 16 b * 12 n-chunks
#define PB_WB  3          // w_score -> bf16
#define PB_HB  1368       // h -> bf16 into compacted A rows (16*456*48/256*... = 1368)
#define PREP_BLOCKS (PB_CUM + PB_TRW + PB_GAT + PB_CC + PB_WB + PB_HB)

typedef __attribute__((ext_vector_type(8))) short short8;
typedef __attribute__((ext_vector_type(16))) float float16v;

__device__ __forceinline__ unsigned short f2bf(float f) {
    __hip_bfloat16 b = __float2bfloat16(f);
    return *(unsigned short*)&b;
}
__device__ __forceinline__ float bf2f(unsigned short u) {
    union { unsigned int i; float f; } v; v.i = ((unsigned int)u) << 16; return v.f;
}
__device__ __forceinline__ void load_lds16(const void* g, void* l) {
    __builtin_amdgcn_global_load_lds((__attribute__((address_space(1))) void*)g,
                                     (__attribute__((address_space(3))) void*)l, 16, 0, 0);
}
__device__ __forceinline__ ushort4 pack4(float4 v) {
    ushort4 o; o.x = f2bf(v.x); o.y = f2bf(v.y); o.z = f2bf(v.z); o.w = f2bf(v.w);
    return o;
}

// branch-free exact-gelu: Abramowitz-Stegun 3-term erf, max err 2.5e-5
__device__ __forceinline__ float gelu_exact(float v) {
    float a = fabsf(v) * 0.70710678118654752f;
    float t = __builtin_amdgcn_rcpf(fmaf(a, 0.47047f, 1.0f));
    float poly = t * fmaf(t, fmaf(t, 0.7478556f, -0.0958798f), 0.3480242f);
    float e = __builtin_amdgcn_exp2f(a * a * -1.4426950408889634f);
    float erfa = fmaf(-poly, e, 1.0f);
    float erfv = copysignf(erfa, v);
    return 0.5f * v * (1.0f + erfv);
}

// ---------------------------------------------------------------------------
// prep mega-kernel: all inter-independent setup in ONE launch.
// ---------------------------------------------------------------------------
__global__ __launch_bounds__(256) void prep_kernel(
    const float4* __restrict__ h4, const float* __restrict__ h,
    const int* __restrict__ starts, const float* __restrict__ W1,
    const float4* __restrict__ w_score,
    float4* __restrict__ partial, __hip_bfloat16* __restrict__ Ab,
    __hip_bfloat16* __restrict__ Wt, float* __restrict__ CC,
    ushort4* __restrict__ wb16) {
    __shared__ float tile[64][65];
    int bx = blockIdx.x, tid = threadIdx.x;

    if (bx < PB_CUM) {
        int idx = bx * 256 + tid;                    // (b, ch, hd4)
        int hd4 = idx % 192; int t = idx / 192; int ch = t % CH_; int b = t / CH_;
        const float4* hp = h4 + ((size_t)b * T_ + ch * CT_) * 192 + hd4;
        float4 acc = {0.f, 0.f, 0.f, 0.f};
#pragma unroll
        for (int tt = 0; tt < CT_; tt++) {
            float4 v = hp[(size_t)tt * 192];
            acc.x += v.x; acc.y += v.y; acc.z += v.z; acc.w += v.w;
        }
        partial[idx] = acc;
    } else if (bx < PB_CUM + PB_TRW) {
        int q = bx - PB_CUM;
        int n0 = (q % 48) * 64, k0 = (q / 48) * 64;
        int c = tid & 63, r0 = tid >> 6;
#pragma unroll
        for (int i = 0; i < 16; i++) {
            int r = r0 + i * 4;
            tile[r][c] = W1[(size_t)(k0 + r) * HS_ + n0 + c];
        }
        __syncthreads();
        int p = k0 / H_, kl = k0 % H_;
        __hip_bfloat16* out = Wt + (size_t)p * HS_ * H_;
#pragma unroll
        for (int i = 0; i < 16; i++) {
            int r = r0 + i * 4;
            out[(size_t)(n0 + r) * H_ + kl + c] = __float2bfloat16(tile[c][r]);
        }
    } else if (bx < PB_CUM + PB_TRW + PB_GAT) {
        int r = bx - (PB_CUM + PB_TRW);              // 0..511 span rows
        int b = r / S_;
        int sv = starts[r];
        int sc = min(max(sv, 0), T_ - 1);
        const float* src = h + (size_t)(b * T_ + sc) * H_;
        __hip_bfloat16* dst = Ab + (size_t)(STB + r) * H_;
        for (int j = tid; j < H_; j += 256)
            dst[j] = __float2bfloat16(src[j]);
    } else if (bx < PB_CUM + PB_TRW + PB_GAT + PB_CC) {
        int q = bx - (PB_CUM + PB_TRW + PB_GAT);
        int b = q / 12, n0 = (q % 12) * 256;
        float* hs = &tile[0][0];                     // reuse LDS (768 floats)
        const float* hrow = h + (size_t)b * T_ * H_; // h[b,0,:]
        for (int j = tid; j < H_; j += 256) hs[j] = hrow[j];
        __syncthreads();
        int d = n0 + tid;
        const float* wp = W1 + (size_t)2304 * HS_ + d;
        float acc = 0.f;
#pragma unroll 8
        for (int k = 0; k < H_; k++) acc = fmaf(hs[k], wp[(size_t)k * HS_], acc);
        CC[(size_t)b * HS_ + d] = acc;
    } else if (bx < PB_CUM + PB_TRW + PB_GAT + PB_CC + PB_WB) {
        int i = (bx - (PB_CUM + PB_TRW + PB_GAT + PB_CC)) * 256 + tid;  // 0..767
        wb16[i] = pack4(w_score[i]);
    } else {
        // h -> bf16 into compacted A rows [0, 7296): 4 float4s per thread
        int flat = (bx - (PB_CUM + PB_TRW + PB_GAT + PB_CC + PB_WB)) * 256 + tid;
        int r = flat / 48;                           // 0..7295 (b*456 + t)
        int c4 = (flat % 48) * 4;
        int b = r / TX_, t = r % TX_;
        const float4* src = h4 + ((size_t)(b * T_ + t)) * 192 + c4;
        ushort4* dst = (ushort4*)Ab + (size_t)r * 192 + c4;
#pragma unroll
        for (int k = 0; k < 4; k++) dst[k] = pack4(src[k]);
    }
}

// pass3: chunk prefix inlined; writes ONLY preb (hb moved to prep). Dead
// chunks early-out.
__global__ __launch_bounds__(256) void cumsum_pass3(const float4* __restrict__ h4,
                                                    const float4* __restrict__ partial,
                                                    ushort4* __restrict__ Ab4) {
    int idx = blockIdx.x * 256 + threadIdx.x;        // (b, ch, hd4)
    int hd4 = idx % 192; int t = idx / 192; int ch = t % CH_; int b = t / CH_;
    if (ch * CT_ >= TX_) return;                     // dead chunk
    float4 acc = {0.f, 0.f, 0.f, 0.f};
#pragma unroll
    for (int c = 0; c < CH_; c++) {
        if (c < ch) {
            float4 v = partial[((size_t)b * CH_ + c) * 192 + hd4];
            acc.x += v.x; acc.y += v.y; acc.z += v.z; acc.w += v.w;
        }
    }
    const float4* hp = h4 + ((size_t)b * T_ + ch * CT_) * 192 + hd4;
    if (ch == 0) {
        ushort4 z = {0, 0, 0, 0};
        Ab4[((size_t)(YB2 + b * TX_)) * 192 + hd4] = z;   // pre[b][0] = 0
    }
#pragma unroll
    for (int tt = 0; tt < CT_; tt++) {
        int t2 = ch * CT_ + tt;
        float4 hv = hp[(size_t)tt * 192];
        acc.x += hv.x; acc.y += hv.y; acc.z += hv.z; acc.w += hv.w;
        if (t2 + 1 < TX_)
            Ab4[((size_t)(YB2 + b * TX_ + t2 + 1)) * 192 + hd4] = pack4(acc);
    }
}

// ---------------------------------------------------------------------------
// mega MFMA GEMM over 15104 compacted A rows (X | Y | ST). ST epilogue fuses
// +CC[b]+b1, writes bf16 c0. 128x128 tile, BK=64, 4 waves, 32x32x16 bf16.
// LDS: [hh][row 128][4 chunks of 16B], physical chunk = logical ^ ((row>>1)&3).
// grid: x = n-tile (24) fastest -> B-slices pin per-XCD L2, A read ~once.
// ---------------------------------------------------------------------------
__global__ __launch_bounds__(256) void mfma_gemm(const __hip_bfloat16* __restrict__ Ab,
                                                 const __hip_bfloat16* __restrict__ Wt,
                                                 const float* __restrict__ CC,
                                                 const float* __restrict__ b1,
                                                 __hip_bfloat16* __restrict__ XY,
                                                 unsigned short* __restrict__ c0b) {
    constexpr int K = H_;
    __shared__ __hip_bfloat16 As[2 * 128 * 32];
    __shared__ __hip_bfloat16 Bs[2 * 128 * 32];
    int tid = threadIdx.x;
    int wave = tid >> 6, lane = tid & 63;
    int n0 = blockIdx.x * 128, m0 = blockIdx.y * 128;
    int wm = (wave & 1) * 64, wn = (wave >> 1) * 64;

    const __hip_bfloat16* Bt;
    if (m0 < YB2)        Bt = Wt + (size_t)1 * HS_ * H_;  // X: h_end panel
    else if (m0 < STB)   Bt = Wt + (size_t)2 * HS_ * H_;  // Y: h_mean panel
    else                 Bt = Wt;                         // ST: h_start panel

    float16v acc[2][2] = {};

    int l31 = lane & 31, lh = lane >> 5;

    for (int k0 = 0; k0 < K; k0 += 64) {
        __syncthreads();
#pragma unroll
        for (int i = 0; i < 4; i++) {
            int cid = i * 256 + wave * 64 + lane;   // 0..1023 physical 16B chunks
            int hh = cid >> 9, row = (cid >> 2) & 127, pc = cid & 3;
            int lc = pc ^ ((row >> 1) & 3);         // logical chunk this slot holds
            size_t go = (size_t)row * K + k0 + hh * 32 + lc * 8;
            load_lds16(Ab + (size_t)m0 * K + go,
                       (char*)As + (size_t)(i * 256 + wave * 64) * 16);
            load_lds16(Bt + (size_t)n0 * K + go,
                       (char*)Bs + (size_t)(i * 256 + wave * 64) * 16);
        }
        __syncthreads();

        const short* Asp = (const short*)As;
        const short* Bsp = (const short*)Bs;
#pragma unroll
        for (int kk = 0; kk < 4; kk++) {
            int hh = kk >> 1;
            int lc = 2 * (kk & 1) + lh;             // logical chunk for this frag
            short8 af[2], bf[2];
#pragma unroll
            for (int mi = 0; mi < 2; mi++) {
                int row = wm + mi * 32 + l31;
                int pc = lc ^ ((row >> 1) & 3);
                af[mi] = *(const short8*)&Asp[(hh * 512 + row * 4 + pc) * 8];
            }
#pragma unroll
            for (int ni = 0; ni < 2; ni++) {
                int row = wn + ni * 32 + l31;
                int pc = lc ^ ((row >> 1) & 3);
                bf[ni] = *(const short8*)&Bsp[(hh * 512 + row * 4 + pc) * 8];
            }
#pragma unroll
            for (int mi = 0; mi < 2; mi++)
#pragma unroll
                for (int ni = 0; ni < 2; ni++)
                    acc[mi][ni] = __builtin_amdgcn_mfma_f32_32x32x16_bf16(
                        af[mi], bf[ni], acc[mi][ni], 0, 0, 0);
        }
    }

    // epilogue: 32x32 C/D layout: col=lane&31, row=(reg&3)+8*(reg>>2)+4*(lane>>5)
#pragma unroll
    for (int mi = 0; mi < 2; mi++) {
#pragma unroll
        for (int ni = 0; ni < 2; ni++) {
            int n = n0 + wn + ni * 32 + l31;
#pragma unroll
            for (int r = 0; r < 16; r++) {
                int m = m0 + wm + mi * 32 + (r & 3) + 8 * (r >> 2) + 4 * lh;
                float v = acc[mi][ni][r];
                if (m < XYROWS) {
                    XY[(size_t)m * HS_ + n] = __float2bfloat16(v);
                } else {
                    int bsI = m - STB;               // 0..511
                    int bb = bsI >> 5;
                    c0b[(size_t)bsI * HS_ + n] =
                        f2bf(v + CC[(size_t)bb * HS_ + n] + b1[n]);
                }
            }
        }
    }
}

// ---------------------------------------------------------------------------
// combine: one wave per (b,s, l-pair); l0=2p, l1=2p+1 share Ys/c0/w streams.
// grid x swizzled so XCD = x%8 = b%8: all spans+pairs of a batch share an XCD
// -> span-row overlap (~3.5x) hits local L2.
// ---------------------------------------------------------------------------
__global__ __launch_bounds__(256) void combine_kernel(
    const unsigned short* __restrict__ c0, const unsigned short* __restrict__ wb16,
    const __hip_bfloat16* __restrict__ XY,
    const float* __restrict__ b_score, const float* __restrict__ W_type,
    const int* __restrict__ starts, const int* __restrict__ ends,
    float* __restrict__ scores, float* __restrict__ tgold) {
    int x = blockIdx.x;
    int b = x & 15, s = x >> 4;          // XCD = x%8 = b%8
    int bs = b * S_ + s;
    int wave = threadIdx.x >> 6, lane = threadIdx.x & 63;
    int pr = blockIdx.y * 4 + wave;        // pair index 0..24
    if (pr >= L_ / 2) return;
    int l0 = pr * 2, l1 = l0 + 1;
    int sv = starts[bs], ev = ends[bs];
    int gi = min(max(ev - sv, 0), L_ - 1);
    int sc = min(max(sv, 0), TX_ - 1);
    int pc0 = min(max(sv + l0, 0), TX_ - 2);   // spec: <=448; clamp keeps in-bounds
    int pc1 = min(max(sv + l1, 0), TX_ - 2);
    float inv0 = 1.0f / (float)(l0 + 1);
    float inv1 = 1.0f / (float)(l1 + 1);
    bool isg0 = (l0 == gi), isg1 = (l1 == gi);
    bool anyg = isg0 || isg1;

    const unsigned short* X0 = (const unsigned short*)(XY + (size_t)(b * TX_ + pc0) * HS_);
    const unsigned short* X1 = (const unsigned short*)(XY + (size_t)(b * TX_ + pc1) * HS_);
    const unsigned short* Y0 = (const unsigned short*)(XY + (size_t)(YB2 + b * TX_ + pc0 + 1) * HS_);
    const unsigned short* Y1 = (const unsigned short*)(XY + (size_t)(YB2 + b * TX_ + pc1 + 1) * HS_);
    const unsigned short* Ysr = (const unsigned short*)(XY + (size_t)(YB2 + b * TX_ + sc) * HS_);
    const unsigned short* c0r = c0 + (size_t)bs * HS_;

    float local0 = 0.f, local1 = 0.f, t0 = 0.f, t1 = 0.f, t2 = 0.f;
#pragma unroll
    for (int j = 0; j < 6; j++) {
        int d = j * 512 + lane * 8;
        short8 xv0 = *(const short8*)(X0 + d);
        short8 xv1 = *(const short8*)(X1 + d);
        short8 yv0 = *(const short8*)(Y0 + d);
        short8 yv1 = *(const short8*)(Y1 + d);
        short8 sv8 = *(const short8*)(Ysr + d);
        short8 cv8 = *(const short8*)(c0r + d);
        short8 wv8 = *(const short8*)(wb16 + d);
#pragma unroll
        for (int q = 0; q < 8; q++) {
            float ys = bf2f(((const unsigned short*)&sv8)[q]);
            float cv = bf2f(((const unsigned short*)&cv8)[q]);
            float w  = bf2f(((const unsigned short*)&wv8)[q]);
            float v0 = fmaf(bf2f(((const unsigned short*)&yv0)[q]) - ys, inv0, cv) +
                       bf2f(((const unsigned short*)&xv0)[q]);
            float v1 = fmaf(bf2f(((const unsigned short*)&yv1)[q]) - ys, inv1, cv) +
                       bf2f(((const unsigned short*)&xv1)[q]);
            float g0 = gelu_exact(v0);
            float g1 = gelu_exact(v1);
            local0 = fmaf(g0, w, local0);
            local1 = fmaf(g1, w, local1);
            if (anyg) {   // wave-uniform branch
                float gg = isg0 ? g0 : g1;
                t0 = fmaf(gg, W_type[(d + q) * NT_ + 0], t0);
                t1 = fmaf(gg, W_type[(d + q) * NT_ + 1], t1);
                t2 = fmaf(gg, W_type[(d + q) * NT_ + 2], t2);
            }
        }
    }
#pragma unroll
    for (int off = 32; off >= 1; off >>= 1) {
        local0 += __shfl_down(local0, off);
        local1 += __shfl_down(local1, off);
    }
    if (lane == 0) {
        float bs0 = b_score[0];
        scores[(size_t)bs * L_ + l0] = local0 + bs0;
        scores[(size_t)bs * L_ + l1] = local1 + bs0;
    }
    if (anyg) {
#pragma unroll
        for (int off = 32; off >= 1; off >>= 1) {
            t0 += __shfl_down(t0, off);
            t1 += __shfl_down(t1, off);
            t2 += __shfl_down(t2, off);
        }
        if (lane == 0) {
            tgold[bs * NT_ + 0] = t0;
            tgold[bs * NT_ + 1] = t1;
            tgold[bs * NT_ + 2] = t2;
        }
    }
}

// ---------------------------------------------------------------------------
// final loss: one block, one thread per (b,s)
// ---------------------------------------------------------------------------
__global__ __launch_bounds__(512) void loss_kernel(
    const float* __restrict__ scores, const float* __restrict__ tgold,
    const int* __restrict__ mask, const int* __restrict__ starts,
    const int* __restrict__ ends, const int* __restrict__ types,
    const float* __restrict__ b_type, float* __restrict__ out) {
    __shared__ int svl[B_];
    __shared__ float r[3][8];
    int tid = threadIdx.x;
    int b = tid / S_;
    if (tid < B_) svl[tid] = 0;
    __syncthreads();
    {
        int part = 0;
        const int* mp = mask + tid * 16;
#pragma unroll
        for (int i = 0; i < 16; i++) part += mp[i];
        atomicAdd(&svl[tid / (T_ / 16)], part);
    }
    __syncthreads();
    int vl = svl[b];
    int lt = max(1, vl - 2);
    int sv = starts[tid], ev = ends[tid];
    int gold = ev - sv;
    bool valid = (sv >= 1) && (sv <= lt) && (ev >= sv) && (ev <= lt) && (gold < L_);
    int emax = min(sv + L_ - 1, lt);
    const float* sp = scores + (size_t)tid * L_;
    float m = -1e30f;
    for (int l = 0; l < L_; l++) {
        float v = (sv + l <= emax) ? sp[l] : -1e9f;
        m = fmaxf(m, v);
    }
    float sum = 0.f;
    for (int l = 0; l < L_; l++) {
        float v = (sv + l <= emax) ? sp[l] : -1e9f;
        sum += expf(v - m);
    }
    int gi = min(max(gold, 0), L_ - 1);
    float vg = (sv + gi <= emax) ? sp[gi] : -1e9f;
    float end_loss = (m + logf(sum)) - vg;

    float t0 = tgold[tid * 3 + 0] + b_type[0];
    float t1 = tgold[tid * 3 + 1] + b_type[1];
    float t2 = tgold[tid * 3 + 2] + b_type[2];
    float tm = fmaxf(t0, fmaxf(t1, t2));
    float tsum = expf(t0 - tm) + expf(t1 - tm) + expf(t2 - tm);
    int tg = min(max(types[tid], 0), NT_ - 1);
    float tv = (tg == 0) ? t0 : ((tg == 1) ? t1 : t2);
    float type_loss = (tm + logf(tsum)) - tv;

    float ve = valid ? end_loss : 0.f;
    float vt = valid ? type_loss : 0.f;
    float vc = valid ? 1.f : 0.f;
    for (int off = 32; off >= 1; off >>= 1) {
        ve += __shfl_down(ve, off);
        vt += __shfl_down(vt, off);
        vc += __shfl_down(vc, off);
    }
    if ((tid & 63) == 0) {
        int w = tid >> 6;
        r[0][w] = ve; r[1][w] = vt; r[2][w] = vc;
    }
    __syncthreads();
    if (tid == 0) {
        float se = 0, st = 0, n = 0;
        for (int w = 0; w < 8; w++) { se += r[0][w]; st += r[1][w]; n += r[2][w]; }
        float denom = fmaxf(n, 1.f);
        out[0] = (n > 0.f) ? (se / denom + st / denom) : 0.f;
    }
}

// ---------------------------------------------------------------------------
extern "C" void kernel_launch(void* const* d_in, const int* in_sizes, int n_in,
                              void* d_out, int out_size, void* d_ws, size_t ws_size,
                              hipStream_t stream) {
    const float* h       = (const float*)d_in[0];
    const int*   mask    = (const int*)d_in[1];
    const int*   starts  = (const int*)d_in[2];
    const int*   ends    = (const int*)d_in[3];
    const int*   types   = (const int*)d_in[4];
    const float* W1      = (const float*)d_in[5];
    const float* b1      = (const float*)d_in[6];
    const float* w_score = (const float*)d_in[7];
    const float* b_score = (const float*)d_in[8];
    const float* W_type  = (const float*)d_in[9];
    const float* b_type  = (const float*)d_in[10];
    float* out = (float*)d_out;

    char* ws = (char*)d_ws;
    size_t off = 0;
    __hip_bfloat16* Ab = (__hip_bfloat16*)(ws + off); off += (size_t)AROWS * H_ * 2;
    __hip_bfloat16* XY = (__hip_bfloat16*)(ws + off); off += (size_t)XYROWS * HS_ * 2;
    __hip_bfloat16* Wt = (__hip_bfloat16*)(ws + off); off += (size_t)3 * HS_ * H_ * 2;
    float* CC     = (float*)(ws + off);               off += (size_t)16 * HS_ * 4;
    unsigned short* c0b = (unsigned short*)(ws + off); off += (size_t)512 * HS_ * 2;
    unsigned short* wb16 = (unsigned short*)(ws + off); off += (size_t)HS_ * 2;
    float* scores = (float*)(ws + off);               off += (size_t)B_ * S_ * L_ * 4;
    float* tgold  = (float*)(ws + off);               off += (size_t)B_ * S_ * NT_ * 4;
    float4* partial = (float4*)XY;  // aliases XY; consumed by pass3 before GEMM writes XY

    hipLaunchKernelGGL(prep_kernel, dim3(PREP_BLOCKS), dim3(256), 0, stream,
                       (const float4*)h, h, starts, W1, (const float4*)w_score,
                       partial, Ab, Wt, CC, (ushort4*)wb16);
    hipLaunchKernelGGL(cumsum_pass3, dim3(B_ * CH_ * 192 / 256), dim3(256), 0, stream,
                       (const float4*)h, (const float4*)partial, (ushort4*)Ab);
    hipLaunchKernelGGL(mfma_gemm, dim3(24, AROWS / 128), dim3(256), 0, stream,
                       Ab, Wt, CC, b1, XY, c0b);
    hipLaunchKernelGGL(combine_kernel, dim3(B_ * S_, 7), dim3(256), 0, stream,
                       c0b, wb16, XY, b_score, W_type, starts, ends, scores, tgold);
    hipLaunchKernelGGL(loss_kernel, dim3(1), dim3(512), 0, stream,
                       scores, tgold, mask, starts, ends, types, b_type, out);
}

// Round 12
// 322.819 us; speedup vs baseline: 1.1267x; 1.0983x over previous
//
#include <hip/hip_runtime.h>
#include <hip/hip_bf16.h>
#include <math.h>

#define B_ 16
#define T_ 512
#define H_ 768
#define S_ 32
#define L_ 50
#define NT_ 3
#define HS_ 3072
#define CH_ 32
#define CT_ 16  // T_/CH_

// Row compaction: starts in [1,400), L=50  =>  pc <= 448, pre-index <= 449.
// TX_=456 rows/batch cover all live rows (safety margin + clamps).
#define TX_ 456
// A-buffer row layout (bf16, 768 cols), compacted:
//   [0, 7296)        hb   = bf16(h[b,t]), row b*456+t, t<456
//   [7296, 14592)    preb = bf16(cumsum), row 7296 + b*456 + u
//   [14592, 15104)   Gb   = gathered span-start rows (512)
//   [15104, 15120)   cls rows (16)
//   [15120, 15232)   pad (staged but discarded)
#define YB2 7296
#define GB 14592
#define CLSB 15104
#define XYROWS 14592
#define AROWS 15232        // = 119 * 128 exactly

typedef __attribute__((ext_vector_type(8))) short short8;
typedef __attribute__((ext_vector_type(16))) float float16v;

__device__ __forceinline__ unsigned short f2bf(float f) {
    __hip_bfloat16 b = __float2bfloat16(f);
    return *(unsigned short*)&b;
}
__device__ __forceinline__ float bf2f(unsigned short u) {
    union { unsigned int i; float f; } v; v.i = ((unsigned int)u) << 16; return v.f;
}
__device__ __forceinline__ void load_lds16(const void* g, void* l) {
    __builtin_amdgcn_global_load_lds((__attribute__((address_space(1))) void*)g,
                                     (__attribute__((address_space(3))) void*)l, 16, 0, 0);
}
__device__ __forceinline__ ushort4 pack4(float4 v) {
    ushort4 o; o.x = f2bf(v.x); o.y = f2bf(v.y); o.z = f2bf(v.z); o.w = f2bf(v.w);
    return o;
}

// branch-free exact-gelu: Abramowitz-Stegun 3-term erf, max err 2.5e-5
__device__ __forceinline__ float gelu_exact(float v) {
    float a = fabsf(v) * 0.70710678118654752f;
    float t = __builtin_amdgcn_rcpf(fmaf(a, 0.47047f, 1.0f));
    float poly = t * fmaf(t, fmaf(t, 0.7478556f, -0.0958798f), 0.3480242f);
    float e = __builtin_amdgcn_exp2f(a * a * -1.4426950408889634f);
    float erfa = fmaf(-poly, e, 1.0f);
    float erfv = copysignf(erfa, v);
    return 0.5f * v * (1.0f + erfv);
}

// ---------------------------------------------------------------------------
// cumsum pass1: per-(b,chunk) partial sums, float4-vectorized over hd
// ---------------------------------------------------------------------------
__global__ __launch_bounds__(256) void cumsum_pass1(const float4* __restrict__ h4,
                                                    float4* __restrict__ partial) {
    int idx = blockIdx.x * 256 + threadIdx.x;        // (b, ch, hd4)
    int hd4 = idx % 192; int t = idx / 192; int ch = t % CH_; int b = t / CH_;
    const float4* hp = h4 + ((size_t)b * T_ + ch * CT_) * 192 + hd4;
    float4 acc = {0.f, 0.f, 0.f, 0.f};
#pragma unroll
    for (int tt = 0; tt < CT_; tt++) {
        float4 v = hp[(size_t)tt * 192];
        acc.x += v.x; acc.y += v.y; acc.z += v.z; acc.w += v.w;
    }
    partial[idx] = acc;
}

// pass3 (chunk prefix folded in): emit bf16 h + bf16 cumsum into compacted A.
// Dead chunks early-out.
__global__ __launch_bounds__(256) void cumsum_pass3(const float4* __restrict__ h4,
                                                    const float4* __restrict__ partial,
                                                    ushort4* __restrict__ Ab4) {
    int idx = blockIdx.x * 256 + threadIdx.x;        // (b, ch, hd4)
    int hd4 = idx % 192; int t = idx / 192; int ch = t % CH_; int b = t / CH_;
    if (ch * CT_ >= TX_) return;                     // dead chunk
    float4 acc = {0.f, 0.f, 0.f, 0.f};
#pragma unroll
    for (int c = 0; c < CH_; c++) {
        if (c < ch) {
            float4 v = partial[((size_t)b * CH_ + c) * 192 + hd4];
            acc.x += v.x; acc.y += v.y; acc.z += v.z; acc.w += v.w;
        }
    }
    const float4* hp = h4 + ((size_t)b * T_ + ch * CT_) * 192 + hd4;
    if (ch == 0) {
        ushort4 z = {0, 0, 0, 0};
        Ab4[((size_t)(YB2 + b * TX_)) * 192 + hd4] = z;   // pre[b][0] = 0
    }
#pragma unroll
    for (int tt = 0; tt < CT_; tt++) {
        int t2 = ch * CT_ + tt;
        float4 hv = hp[(size_t)tt * 192];
        if (t2 < TX_)
            Ab4[((size_t)(b * TX_ + t2)) * 192 + hd4] = pack4(hv);
        acc.x += hv.x; acc.y += hv.y; acc.z += hv.z; acc.w += hv.w;
        if (t2 + 1 < TX_)
            Ab4[((size_t)(YB2 + b * TX_ + t2 + 1)) * 192 + hd4] = pack4(acc);
    }
}

// ---------------------------------------------------------------------------
// gather span-start rows (512) + cls rows (16) into A
// ---------------------------------------------------------------------------
__global__ void gather_kernel(const float* __restrict__ h,
                              const int* __restrict__ starts,
                              __hip_bfloat16* __restrict__ Ab) {
    int r = blockIdx.x;
    int src_row, dst_row;
    if (r < B_ * S_) {
        int b = r / S_;
        int sv = starts[r];
        int sc = min(max(sv, 0), T_ - 1);
        src_row = b * T_ + sc;
        dst_row = GB + r;
    } else {
        int b = r - B_ * S_;
        src_row = b * T_;
        dst_row = CLSB + b;
    }
    __hip_bfloat16* dst = Ab + (size_t)dst_row * H_;
    const float* src = h + (size_t)src_row * H_;
    for (int j = threadIdx.x; j < H_; j += 256)
        dst[j] = __float2bfloat16(src[j]);
}

// ---------------------------------------------------------------------------
// W1 (3072x3072 fp32) -> 4 transposed bf16 panels Wt[p][n=3072][k=768]
// ---------------------------------------------------------------------------
__global__ __launch_bounds__(256) void transpose_w(const float* __restrict__ W1,
                                                   __hip_bfloat16* __restrict__ Wt) {
    __shared__ float tile[64][65];
    int n0 = blockIdx.x * 64, k0 = blockIdx.y * 64;
    int c = threadIdx.x & 63, r0 = threadIdx.x >> 6;
#pragma unroll
    for (int i = 0; i < 16; i++) {
        int r = r0 + i * 4;
        tile[r][c] = W1[(size_t)(k0 + r) * HS_ + n0 + c];
    }
    __syncthreads();
    int p = k0 / H_, kl = k0 % H_;
    __hip_bfloat16* out = Wt + (size_t)p * HS_ * H_;
#pragma unroll
    for (int i = 0; i < 16; i++) {
        int r = r0 + i * 4;
        out[(size_t)(n0 + r) * H_ + kl + c] = __float2bfloat16(tile[c][r]);
    }
}

// ---------------------------------------------------------------------------
// mega MFMA GEMM over 15232 compacted A rows (X | Y | ST | CC | pad).
// 128x128 tile, BK=64, 4 waves (2x2), each wave 2x2 tiles of 32x32x16 bf16.
// LDS: [hh][row 128][4 chunks of 16B], physical chunk = logical ^ ((row>>1)&3).
// grid: x = n-tile (24) fastest -> B-slices pin per-XCD L2, A read ~once.
// ---------------------------------------------------------------------------
__global__ __launch_bounds__(256) void mfma_gemm(const __hip_bfloat16* __restrict__ Ab,
                                                 const __hip_bfloat16* __restrict__ Wt,
                                                 __hip_bfloat16* __restrict__ XY,
                                                 float* __restrict__ ST,
                                                 float* __restrict__ CC) {
    constexpr int K = H_;
    __shared__ __hip_bfloat16 As[2 * 128 * 32];
    __shared__ __hip_bfloat16 Bs[2 * 128 * 32];
    int tid = threadIdx.x;
    int wave = tid >> 6, lane = tid & 63;
    int n0 = blockIdx.x * 128, m0 = blockIdx.y * 128;
    int wm = (wave & 1) * 64, wn = (wave >> 1) * 64;

    const __hip_bfloat16* Bt;
    if (m0 < YB2)        Bt = Wt + (size_t)1 * HS_ * H_;  // X: h_end panel
    else if (m0 < GB)    Bt = Wt + (size_t)2 * HS_ * H_;  // Y: h_mean panel
    else if (m0 < CLSB)  Bt = Wt;                         // ST: h_start panel
    else                 Bt = Wt + (size_t)3 * HS_ * H_;  // CC: cls panel

    float16v acc[2][2] = {};

    int l31 = lane & 31, lh = lane >> 5;

    for (int k0 = 0; k0 < K; k0 += 64) {
        __syncthreads();
#pragma unroll
        for (int i = 0; i < 4; i++) {
            int cid = i * 256 + wave * 64 + lane;   // 0..1023 physical 16B chunks
            int hh = cid >> 9, row = (cid >> 2) & 127, pc = cid & 3;
            int lc = pc ^ ((row >> 1) & 3);         // logical chunk this slot holds
            size_t go = (size_t)row * K + k0 + hh * 32 + lc * 8;
            load_lds16(Ab + (size_t)m0 * K + go,
                       (char*)As + (size_t)(i * 256 + wave * 64) * 16);
            load_lds16(Bt + (size_t)n0 * K + go,
                       (char*)Bs + (size_t)(i * 256 + wave * 64) * 16);
        }
        __syncthreads();

        const short* Asp = (const short*)As;
        const short* Bsp = (const short*)Bs;
#pragma unroll
        for (int kk = 0; kk < 4; kk++) {
            int hh = kk >> 1;
            int lc = 2 * (kk & 1) + lh;             // logical chunk for this frag
            short8 af[2], bf[2];
#pragma unroll
            for (int mi = 0; mi < 2; mi++) {
                int row = wm + mi * 32 + l31;
                int pc = lc ^ ((row >> 1) & 3);
                af[mi] = *(const short8*)&Asp[(hh * 512 + row * 4 + pc) * 8];
            }
#pragma unroll
            for (int ni = 0; ni < 2; ni++) {
                int row = wn + ni * 32 + l31;
                int pc = lc ^ ((row >> 1) & 3);
                bf[ni] = *(const short8*)&Bsp[(hh * 512 + row * 4 + pc) * 8];
            }
#pragma unroll
            for (int mi = 0; mi < 2; mi++)
#pragma unroll
                for (int ni = 0; ni < 2; ni++)
                    acc[mi][ni] = __builtin_amdgcn_mfma_f32_32x32x16_bf16(
                        af[mi], bf[ni], acc[mi][ni], 0, 0, 0);
        }
    }

    // epilogue: 32x32 C/D layout: col=lane&31, row=(reg&3)+8*(reg>>2)+4*(lane>>5)
#pragma unroll
    for (int mi = 0; mi < 2; mi++) {
#pragma unroll
        for (int ni = 0; ni < 2; ni++) {
            int n = n0 + wn + ni * 32 + l31;
#pragma unroll
            for (int r = 0; r < 16; r++) {
                int m = m0 + wm + mi * 32 + (r & 3) + 8 * (r >> 2) + 4 * lh;
                float v = acc[mi][ni][r];
                if (m < XYROWS) {
                    XY[(size_t)m * HS_ + n] = __float2bfloat16(v);
                } else if (m < CLSB) {
                    ST[(size_t)(m - GB) * HS_ + n] = v;
                } else if (m < CLSB + 16) {
                    CC[(size_t)(m - CLSB) * HS_ + n] = v;
                }
            }
        }
    }
}

// ---------------------------------------------------------------------------
// c0 = bf16(ST + CC[b] + b1); tail blocks convert w_score -> bf16
// ---------------------------------------------------------------------------
__global__ __launch_bounds__(256) void c0_kernel(const float4* __restrict__ ST,
                                                 const float4* __restrict__ CC,
                                                 const float4* __restrict__ b1,
                                                 const float4* __restrict__ w_score,
                                                 ushort4* __restrict__ c0b,
                                                 ushort4* __restrict__ wb16) {
    if (blockIdx.x >= 512 * HS_ / 4 / 256) {
        int i = (blockIdx.x - 512 * HS_ / 4 / 256) * 256 + threadIdx.x;  // 0..767
        wb16[i] = pack4(w_score[i]);
        return;
    }
    int i = blockIdx.x * 256 + threadIdx.x;  // over 512*768 float4s
    int row = i / (HS_ / 4);
    int b = row >> 5;
    int c4 = i % (HS_ / 4);
    float4 s = ST[i], c = CC[b * (HS_ / 4) + c4], bb = b1[c4];
    float4 v = {s.x + c.x + bb.x, s.y + c.y + bb.y, s.z + c.z + bb.z, s.w + c.w + bb.w};
    c0b[i] = pack4(v);
}

// ---------------------------------------------------------------------------
// combine: one wave per (b,s, l-pair); l0=2p, l1=2p+1 share Ys/c0/w streams.
// grid x swizzled so XCD = x%8 = b%8 (batch's span rows share an XCD L2).
// ---------------------------------------------------------------------------
__global__ __launch_bounds__(256) void combine_kernel(
    const unsigned short* __restrict__ c0, const unsigned short* __restrict__ wb16,
    const __hip_bfloat16* __restrict__ XY,
    const float* __restrict__ b_score, const float* __restrict__ W_type,
    const int* __restrict__ starts, const int* __restrict__ ends,
    float* __restrict__ scores, float* __restrict__ tgold) {
    int x = blockIdx.x;
    int b = x & 15, s = x >> 4;          // XCD = x%8 = b%8
    int bs = b * S_ + s;
    int wave = threadIdx.x >> 6, lane = threadIdx.x & 63;
    int pr = blockIdx.y * 4 + wave;        // pair index 0..24
    if (pr >= L_ / 2) return;
    int l0 = pr * 2, l1 = l0 + 1;
    int sv = starts[bs], ev = ends[bs];
    int gi = min(max(ev - sv, 0), L_ - 1);
    int sc = min(max(sv, 0), TX_ - 1);
    int pc0 = min(max(sv + l0, 0), TX_ - 2);   // spec: <=448; clamp keeps in-bounds
    int pc1 = min(max(sv + l1, 0), TX_ - 2);
    float inv0 = 1.0f / (float)(l0 + 1);
    float inv1 = 1.0f / (float)(l1 + 1);
    bool isg0 = (l0 == gi), isg1 = (l1 == gi);
    bool anyg = isg0 || isg1;

    const unsigned short* X0 = (const unsigned short*)(XY + (size_t)(b * TX_ + pc0) * HS_);
    const unsigned short* X1 = (const unsigned short*)(XY + (size_t)(b * TX_ + pc1) * HS_);
    const unsigned short* Y0 = (const unsigned short*)(XY + (size_t)(YB2 + b * TX_ + pc0 + 1) * HS_);
    const unsigned short* Y1 = (const unsigned short*)(XY + (size_t)(YB2 + b * TX_ + pc1 + 1) * HS_);
    const unsigned short* Ysr = (const unsigned short*)(XY + (size_t)(YB2 + b * TX_ + sc) * HS_);
    const unsigned short* c0r = c0 + (size_t)bs * HS_;

    float local0 = 0.f, local1 = 0.f, t0 = 0.f, t1 = 0.f, t2 = 0.f;
#pragma unroll
    for (int j = 0; j < 6; j++) {
        int d = j * 512 + lane * 8;
        short8 xv0 = *(const short8*)(X0 + d);
        short8 xv1 = *(const short8*)(X1 + d);
        short8 yv0 = *(const short8*)(Y0 + d);
        short8 yv1 = *(const short8*)(Y1 + d);
        short8 sv8 = *(const short8*)(Ysr + d);
        short8 cv8 = *(const short8*)(c0r + d);
        short8 wv8 = *(const short8*)(wb16 + d);
#pragma unroll
        for (int q = 0; q < 8; q++) {
            float ys = bf2f(((const unsigned short*)&sv8)[q]);
            float cv = bf2f(((const unsigned short*)&cv8)[q]);
            float w  = bf2f(((const unsigned short*)&wv8)[q]);
            float v0 = fmaf(bf2f(((const unsigned short*)&yv0)[q]) - ys, inv0, cv) +
                       bf2f(((const unsigned short*)&xv0)[q]);
            float v1 = fmaf(bf2f(((const unsigned short*)&yv1)[q]) - ys, inv1, cv) +
                       bf2f(((const unsigned short*)&xv1)[q]);
            float g0 = gelu_exact(v0);
            float g1 = gelu_exact(v1);
            local0 = fmaf(g0, w, local0);
            local1 = fmaf(g1, w, local1);
            if (anyg) {   // wave-uniform branch
                float gg = isg0 ? g0 : g1;
                t0 = fmaf(gg, W_type[(d + q) * NT_ + 0], t0);
                t1 = fmaf(gg, W_type[(d + q) * NT_ + 1], t1);
                t2 = fmaf(gg, W_type[(d + q) * NT_ + 2], t2);
            }
        }
    }
#pragma unroll
    for (int off = 32; off >= 1; off >>= 1) {
        local0 += __shfl_down(local0, off);
        local1 += __shfl_down(local1, off);
    }
    if (lane == 0) {
        float bs0 = b_score[0];
        scores[(size_t)bs * L_ + l0] = local0 + bs0;
        scores[(size_t)bs * L_ + l1] = local1 + bs0;
    }
    if (anyg) {
#pragma unroll
        for (int off = 32; off >= 1; off >>= 1) {
            t0 += __shfl_down(t0, off);
            t1 += __shfl_down(t1, off);
            t2 += __shfl_down(t2, off);
        }
        if (lane == 0) {
            tgold[bs * NT_ + 0] = t0;
            tgold[bs * NT_ + 1] = t1;
            tgold[bs * NT_ + 2] = t2;
        }
    }
}

// ---------------------------------------------------------------------------
// final loss: one block, one thread per (b,s)
// ---------------------------------------------------------------------------
__global__ __launch_bounds__(512) void loss_kernel(
    const float* __restrict__ scores, const float* __restrict__ tgold,
    const int* __restrict__ mask, const int* __restrict__ starts,
    const int* __restrict__ ends, const int* __restrict__ types,
    const float* __restrict__ b_type, float* __restrict__ out) {
    __shared__ int svl[B_];
    __shared__ float r[3][8];
    int tid = threadIdx.x;
    int b = tid / S_;
    if (tid < B_) svl[tid] = 0;
    __syncthreads();
    {
        int part = 0;
        const int* mp = mask + tid * 16;
#pragma unroll
        for (int i = 0; i < 16; i++) part += mp[i];
        atomicAdd(&svl[tid / (T_ / 16)], part);
    }
    __syncthreads();
    int vl = svl[b];
    int lt = max(1, vl - 2);
    int sv = starts[tid], ev = ends[tid];
    int gold = ev - sv;
    bool valid = (sv >= 1) && (sv <= lt) && (ev >= sv) && (ev <= lt) && (gold < L_);
    int emax = min(sv + L_ - 1, lt);
    const float* sp = scores + (size_t)tid * L_;
    float m = -1e30f;
    for (int l = 0; l < L_; l++) {
        float v = (sv + l <= emax) ? sp[l] : -1e9f;
        m = fmaxf(m, v);
    }
    float sum = 0.f;
    for (int l = 0; l < L_; l++) {
        float v = (sv + l <= emax) ? sp[l] : -1e9f;
        sum += expf(v - m);
    }
    int gi = min(max(gold, 0), L_ - 1);
    float vg = (sv + gi <= emax) ? sp[gi] : -1e9f;
    float end_loss = (m + logf(sum)) - vg;

    float t0 = tgold[tid * 3 + 0] + b_type[0];
    float t1 = tgold[tid * 3 + 1] + b_type[1];
    float t2 = tgold[tid * 3 + 2] + b_type[2];
    float tm = fmaxf(t0, fmaxf(t1, t2));
    float tsum = expf(t0 - tm) + expf(t1 - tm) + expf(t2 - tm);
    int tg = min(max(types[tid], 0), NT_ - 1);
    float tv = (tg == 0) ? t0 : ((tg == 1) ? t1 : t2);
    float type_loss = (tm + logf(tsum)) - tv;

    float ve = valid ? end_loss : 0.f;
    float vt = valid ? type_loss : 0.f;
    float vc = valid ? 1.f : 0.f;
    for (int off = 32; off >= 1; off >>= 1) {
        ve += __shfl_down(ve, off);
        vt += __shfl_down(vt, off);
        vc += __shfl_down(vc, off);
    }
    if ((tid & 63) == 0) {
        int w = tid >> 6;
        r[0][w] = ve; r[1][w] = vt; r[2][w] = vc;
    }
    __syncthreads();
    if (tid == 0) {
        float se = 0, st = 0, n = 0;
        for (int w = 0; w < 8; w++) { se += r[0][w]; st += r[1][w]; n += r[2][w]; }
        float denom = fmaxf(n, 1.f);
        out[0] = (n > 0.f) ? (se / denom + st / denom) : 0.f;
    }
}

// ---------------------------------------------------------------------------
extern "C" void kernel_launch(void* const* d_in, const int* in_sizes, int n_in,
                              void* d_out, int out_size, void* d_ws, size_t ws_size,
                              hipStream_t stream) {
    const float* h       = (const float*)d_in[0];
    const int*   mask    = (const int*)d_in[1];
    const int*   starts  = (const int*)d_in[2];
    const int*   ends    = (const int*)d_in[3];
    const int*   types   = (const int*)d_in[4];
    const float* W1      = (const float*)d_in[5];
    const float* b1      = (const float*)d_in[6];
    const float* w_score = (const float*)d_in[7];
    const float* b_score = (const float*)d_in[8];
    const float* W_type  = (const float*)d_in[9];
    const float* b_type  = (const float*)d_in[10];
    float* out = (float*)d_out;

    char* ws = (char*)d_ws;
    size_t off = 0;
    __hip_bfloat16* Ab = (__hip_bfloat16*)(ws + off); off += (size_t)AROWS * H_ * 2;
    __hip_bfloat16* XY = (__hip_bfloat16*)(ws + off); off += (size_t)XYROWS * HS_ * 2;
    __hip_bfloat16* Wt = (__hip_bfloat16*)(ws + off); off += (size_t)4 * HS_ * H_ * 2;
    float* ST     = (float*)(ws + off);               off += (size_t)512 * HS_ * 4;
    float* CC     = (float*)(ws + off);               off += (size_t)16 * HS_ * 4;
    unsigned short* c0b = (unsigned short*)(ws + off); off += (size_t)512 * HS_ * 2;
    unsigned short* wb16 = (unsigned short*)(ws + off); off += (size_t)HS_ * 2;
    float* scores = (float*)(ws + off);               off += (size_t)B_ * S_ * L_ * 4;
    float* tgold  = (float*)(ws + off);               off += (size_t)B_ * S_ * NT_ * 4;
    float4* partial = (float4*)XY;  // aliases XY; consumed by pass3 before GEMM writes XY

    hipLaunchKernelGGL(cumsum_pass1, dim3(B_ * CH_ * 192 / 256), dim3(256), 0, stream,
                       (const float4*)h, partial);
    hipLaunchKernelGGL(cumsum_pass3, dim3(B_ * CH_ * 192 / 256), dim3(256), 0, stream,
                       (const float4*)h, (const float4*)partial, (ushort4*)Ab);
    hipLaunchKernelGGL(gather_kernel, dim3(B_ * S_ + B_), dim3(256), 0, stream, h, starts, Ab);
    hipLaunchKernelGGL(transpose_w, dim3(48, 48), dim3(256), 0, stream, W1, Wt);
    hipLaunchKernelGGL(mfma_gemm, dim3(24, AROWS / 128), dim3(256), 0, stream,
                       Ab, Wt, XY, ST, CC);
    hipLaunchKernelGGL(c0_kernel, dim3(512 * HS_ / 4 / 256 + 3), dim3(256), 0, stream,
                       (const float4*)ST, (const float4*)CC, (const float4*)b1,
                       (const float4*)w_score, (ushort4*)c0b, (ushort4*)wb16);
    hipLaunchKernelGGL(combine_kernel, dim3(B_ * S_, 7), dim3(256), 0, stream,
                       c0b, wb16, XY, b_score, W_type, starts, ends, scores, tgold);
    hipLaunchKernelGGL(loss_kernel, dim3(1), dim3(512), 0, stream,
                       scores, tgold, mask, starts, ends, types, b_type, out);
}